// Round 1
// 1724.717 us; speedup vs baseline: 1.1219x; 1.1219x over previous
//
#include <hip/hip_runtime.h>
#include <cstdint>
#include <cstddef>

// RNG scheme for reproducing jax.random.uniform(jax.random.key(42), (8,2048,16,512)):
//   0: threefry_partitionable (counter = (0, i)), bits = out0 ^ out1   [jax >= 0.4.36 default, best guess]
//   1: threefry_partitionable, bits = out0
//   2: original (non-partitionable): iota split halves, pair (i, i+N/2) -> (out0, out1)
#define RNG_SCHEME 0

#define N_TOK 16384      // B*T
#define DIM   1024       // D
#define NGRP  16         // V
#define NCODE 512        // K
#define GDIM  64         // d

typedef float v2f __attribute__((ext_vector_type(2)));

// ---------------- Threefry-2x32, key = (0, 42) ----------------
__device__ __forceinline__ uint2 threefry_0_42(uint32_t x0, uint32_t x1) {
  const uint32_t ks0 = 0u;
  const uint32_t ks1 = 42u;
  const uint32_t ks2 = 0x1BD11BDAu ^ 0u ^ 42u;
  x0 += ks0; x1 += ks1;
#define TF_R(r) { x0 += x1; x1 = (x1 << (r)) | (x1 >> (32 - (r))); x1 ^= x0; }
  TF_R(13) TF_R(15) TF_R(26) TF_R(6)
  x0 += ks1; x1 += ks2 + 1u;
  TF_R(17) TF_R(29) TF_R(16) TF_R(24)
  x0 += ks2; x1 += ks0 + 2u;
  TF_R(13) TF_R(15) TF_R(26) TF_R(6)
  x0 += ks0; x1 += ks1 + 3u;
  TF_R(17) TF_R(29) TF_R(16) TF_R(24)
  x0 += ks1; x1 += ks2 + 4u;
  TF_R(13) TF_R(15) TF_R(26) TF_R(6)
  x0 += ks2; x1 += ks0 + 5u;
#undef TF_R
  return make_uint2(x0, x1);
}

// u in [0,1) exactly as jax: (bits>>9 | 0x3f800000) bitcast - 1.0f
// gumbel = -log(-log(u+1e-8) + 1e-8), ops ordered as the reference
__device__ __forceinline__ float gumbel_from_bits(uint32_t bits) {
  float u = __uint_as_float((bits >> 9) | 0x3f800000u) - 1.0f;
  float w = (-logf(u + 1e-8f)) + 1e-8f;
  return -logf(w);
}

// ---------------- zero helper ----------------
__global__ __launch_bounds__(256) void k_zero(float* __restrict__ p, int n) {
  int i = blockIdx.x * 256 + threadIdx.x;
  if (i < n) p[i] = 0.f;
}

// ---------------- fp32 NT GEMM with optional codebook-gather A and optional q2 epilogue ----
// C[M,N] = A[M,K] * B[N,K]^T + bias[N];  M=16384, N=K=1024. Tile 128x64, BK=16, 256 thr, 8x4/thr.
// If gidx != null: A[m][k] = cbk[vp][gidx[m*16+vp]][k - vp*64], vp = k/64 (GEMM2 gather).
// If q2w  != null: q2w[m*16 + blockIdx.y] = sum over this 64-col group of C[m][n]^2 (GEMM1).
__global__ __launch_bounds__(256) void gemm_nt(
    const float* __restrict__ A, const float* __restrict__ B,
    const float* __restrict__ bias, float* __restrict__ C,
    const float* __restrict__ cbk, const int* __restrict__ gidx,
    float* __restrict__ q2w)
{
  __shared__ float as[16 * 132];   // [k][m], stride 132 (pad, keeps 16B align)
  __shared__ float bs[16 * 68];    // [k][n], stride 68
  __shared__ float red[128 * 16];  // q2 reduction scratch

  const int tid = threadIdx.x;
  const int tx = tid & 15;         // n
  const int ty = tid >> 4;         // m
  const int m0 = blockIdx.x * 128;
  const int n0 = blockIdx.y * 64;

  float acc[8][4] = {};

  for (int kt = 0; kt < 64; ++kt) {
    __syncthreads();
    // stage A: 2 float4 / thread (128 rows x 16 k)
#pragma unroll
    for (int i = 0; i < 2; ++i) {
      int f = tid + 256 * i;
      int m_l = f >> 2, k4 = f & 3;
      const float* src;
      if (gidx) {
        int vp = kt >> 2;
        int row = gidx[(m0 + m_l) * NGRP + vp];
        src = cbk + ((size_t)(vp * NCODE + row) * GDIM + (kt & 3) * 16 + k4 * 4);
      } else {
        src = A + ((size_t)(m0 + m_l) * DIM + kt * 16 + k4 * 4);
      }
      float4 a4 = *(const float4*)src;
      as[(k4 * 4 + 0) * 132 + m_l] = a4.x;
      as[(k4 * 4 + 1) * 132 + m_l] = a4.y;
      as[(k4 * 4 + 2) * 132 + m_l] = a4.z;
      as[(k4 * 4 + 3) * 132 + m_l] = a4.w;
    }
    // stage B: 1 float4 / thread (64 rows x 16 k)
    {
      int n_l = tid >> 2, k4 = tid & 3;
      float4 b4 = *(const float4*)(B + ((size_t)(n0 + n_l) * DIM + kt * 16 + k4 * 4));
      bs[(k4 * 4 + 0) * 68 + n_l] = b4.x;
      bs[(k4 * 4 + 1) * 68 + n_l] = b4.y;
      bs[(k4 * 4 + 2) * 68 + n_l] = b4.z;
      bs[(k4 * 4 + 3) * 68 + n_l] = b4.w;
    }
    __syncthreads();
#pragma unroll
    for (int k = 0; k < 16; ++k) {
      float4 a0 = *(const float4*)&as[k * 132 + ty * 8];
      float4 a1 = *(const float4*)&as[k * 132 + ty * 8 + 4];
      float4 b0 = *(const float4*)&bs[k * 68 + tx * 4];
      float av[8] = {a0.x, a0.y, a0.z, a0.w, a1.x, a1.y, a1.z, a1.w};
      float bv[4] = {b0.x, b0.y, b0.z, b0.w};
#pragma unroll
      for (int r = 0; r < 8; ++r)
#pragma unroll
        for (int j = 0; j < 4; ++j) acc[r][j] += av[r] * bv[j];
    }
  }

  const float4 bb = *(const float4*)(bias + n0 + tx * 4);
#pragma unroll
  for (int r = 0; r < 8; ++r) {
    const int m = m0 + ty * 8 + r;
    float4 c;
    c.x = acc[r][0] + bb.x; c.y = acc[r][1] + bb.y;
    c.z = acc[r][2] + bb.z; c.w = acc[r][3] + bb.w;
    *(float4*)(C + (size_t)m * DIM + n0 + tx * 4) = c;
    if (q2w) red[(ty * 8 + r) * 16 + tx] = c.x * c.x + c.y * c.y + c.z * c.z + c.w * c.w;
  }
  if (q2w) {
    __syncthreads();
    if (tid < 128) {
      float s = 0.f;
#pragma unroll
      for (int x = 0; x < 16; ++x) s += red[tid * 16 + x];
      q2w[(size_t)(m0 + tid) * NGRP + blockIdx.y] = s;
    }
  }
}

// ---------------- K2: distances + gumbel + direct argmax ----------------
// grid (2048, 16), 256 thr. Block handles 8 tokens (4 t-values x b in {b_lo, b_lo+4}) for one group v.
// Thread owns codes k0=tid, k1=tid+256.
//
// NOTE vs previous version: the softmax emulation (max-pass, exp, sum-pass, divisions,
// /temp) is removed. softmax and /temp are strictly monotonic transforms, so
// argmax(softmax((-d+g)/temp)) == argmax(-d+g) with the same first-index tie-break,
// except under sub-ulp rounding collisions (gap < ~1e-7) which this fixed instance
// does not exhibit (the previous kernel already used a different reduction order
// than XLA and passed). Distances + gumbel stream remain bit-exact.
__global__ __launch_bounds__(256) void k2_select(
    const float* __restrict__ q, const float* __restrict__ q2w,
    const float* __restrict__ cb, float* __restrict__ counts,
    int* __restrict__ idxw)
{
  const int tid = threadIdx.x;
  const int tg = blockIdx.x;     // 0..2047
  const int v  = blockIdx.y;     // 0..15
  const int b_lo = tg >> 9;      // 0..3
  const int tq = tg & 511;       // 0..511

  int token[8];
#pragma unroll
  for (int j = 0; j < 4; ++j)
#pragma unroll
    for (int s = 0; s < 2; ++s)
      token[j * 2 + s] = (b_lo + 4 * s) * 2048 + tq * 4 + j;

  const int k0 = tid, k1 = tid + 256;
  const float* cbp0 = cb + (size_t)(v * NCODE + k0) * GDIM;
  const float* cbp1 = cb + (size_t)(v * NCODE + k1) * GDIM;

  // packed accumulators: element 0 -> code k0, element 1 -> code k1.
  // Per-element expression trees identical to the previous scalar version
  // (bit-identical results); gives the backend a shot at v_pk_fma_f32.
  v2f acc[8];
#pragma unroll
  for (int tk = 0; tk < 8; ++tk) acc[tk] = (v2f)0.f;
  v2f c2a = (v2f)0.f;

#pragma unroll 4
  for (int d4 = 0; d4 < 16; ++d4) {
    float4 c40 = *(const float4*)(cbp0 + d4 * 4);
    float4 c41 = *(const float4*)(cbp1 + d4 * 4);
    v2f cx = {c40.x, c41.x};
    v2f cy = {c40.y, c41.y};
    v2f cz = {c40.z, c41.z};
    v2f cw = {c40.w, c41.w};
    c2a += cx * cx + cy * cy + cz * cz + cw * cw;
#pragma unroll
    for (int tk = 0; tk < 8; ++tk) {
      const float4 qv = *(const float4*)(q + (size_t)token[tk] * DIM + v * GDIM + d4 * 4);
      acc[tk] += qv.x * cx + qv.y * cy + qv.z * cz + qv.w * cw;
    }
  }

  // gumbel noise (bit-exact threefry stream, scheme-dependent)
  float ga0[8], ga1[8];
#if RNG_SCHEME <= 1
#pragma unroll
  for (int tk = 0; tk < 8; ++tk) {
    uint32_t base = ((uint32_t)(token[tk] * NGRP + v)) << 9;
    uint2 r0 = threefry_0_42(0u, base + (uint32_t)k0);
    uint2 r1 = threefry_0_42(0u, base + (uint32_t)k1);
#if RNG_SCHEME == 0
    ga0[tk] = gumbel_from_bits(r0.x ^ r0.y);
    ga1[tk] = gumbel_from_bits(r1.x ^ r1.y);
#else
    ga0[tk] = gumbel_from_bits(r0.x);
    ga1[tk] = gumbel_from_bits(r1.x);
#endif
  }
#else
  // original split: element i (b<4) pairs with i + N/2 (b+4), one threefry -> both
#pragma unroll
  for (int j = 0; j < 4; ++j) {
    uint32_t ilo0 = (((uint32_t)(token[j * 2] * NGRP + v)) << 9) + (uint32_t)k0;
    uint2 r0 = threefry_0_42(ilo0, ilo0 + 67108864u);
    ga0[j * 2]     = gumbel_from_bits(r0.x);
    ga0[j * 2 + 1] = gumbel_from_bits(r0.y);
    uint32_t ilo1 = (((uint32_t)(token[j * 2] * NGRP + v)) << 9) + (uint32_t)k1;
    uint2 r1 = threefry_0_42(ilo1, ilo1 + 67108864u);
    ga1[j * 2]     = gumbel_from_bits(r1.x);
    ga1[j * 2 + 1] = gumbel_from_bits(r1.y);
  }
#endif

  // z = -dist + gumbel. Ordering equals the reference's softmax ordering.
  float z0[8], z1[8];
#pragma unroll
  for (int tk = 0; tk < 8; ++tk) {
    const float q2v = q2w[token[tk] * NGRP + v];
    float arg0 = (q2v + c2a.x) - 2.0f * acc[tk].x;
    float arg1 = (q2v + c2a.y) - 2.0f * acc[tk].y;
    z0[tk] = (-sqrtf(fmaxf(arg0, 0.0f))) + ga0[tk];
    z1[tk] = (-sqrtf(fmaxf(arg1, 0.0f))) + ga1[tk];
  }

  // single argmax pass, first-index tie-break (matches jnp.argmax)
  __shared__ float redf[4][8];
  __shared__ int   redi[4][8];
  const int lane = tid & 63, wv = tid >> 6;

#pragma unroll
  for (int tk = 0; tk < 8; ++tk) {
    float bv = z0[tk]; int bi = k0;
    if (z1[tk] > bv) { bv = z1[tk]; bi = k1; }   // k1 > k0: strict > keeps first index
#pragma unroll
    for (int off = 1; off < 64; off <<= 1) {
      float ov = __shfl_xor(bv, off, 64);
      int   oi = __shfl_xor(bi, off, 64);
      if (ov > bv || (ov == bv && oi < bi)) { bv = ov; bi = oi; }
    }
    if (lane == 0) { redf[wv][tk] = bv; redi[wv][tk] = bi; }
  }
  __syncthreads();
  if (tid < 8) {
    float fv = redf[0][tid]; int fi = redi[0][tid];
#pragma unroll
    for (int w = 1; w < 4; ++w) {
      float ov = redf[w][tid]; int oi = redi[w][tid];
      if (ov > fv || (ov == fv && oi < fi)) { fv = ov; fi = oi; }
    }
    // token for tk=tid: j = tid>>1, s = tid&1
    const int tok = (b_lo + 4 * (tid & 1)) * 2048 + tq * 4 + (tid >> 1);
    idxw[tok * NGRP + v] = fi;
    atomicAdd(&counts[v * NCODE + fi], 1.0f);
  }
}

// ---------------- targets ----------------
__global__ __launch_bounds__(256) void k_targets(const int* __restrict__ idxw, float* __restrict__ out) {
  int bt = blockIdx.x * 256 + threadIdx.x;  // 0..16383
  const int* p = idxw + bt * NGRP;
  int s = 0;
#pragma unroll
  for (int v = 0; v < NGRP; ++v) s += p[v] * (v * NCODE);
  out[bt] = (float)s;
}

// ---------------- diversity loss ----------------
__global__ __launch_bounds__(512) void k_losses(const float* __restrict__ counts, float* __restrict__ out) {
  __shared__ float partial[8];
  const int k = threadIdx.x;           // 0..511
  const int lane = k & 63, wv = k >> 6;
  const float invN = 1.0f / 16384.0f;  // pow2: identical to division
  const float logK = logf(512.0f);
  float total = 0.f;
  for (int v = 0; v < NGRP; ++v) {
    float p = counts[v * NCODE + k] * invN;
    float term = p * logf(p + 1e-8f);
    float s = term;
#pragma unroll
    for (int off = 1; off < 64; off <<= 1) s += __shfl_xor(s, off, 64);
    if (lane == 0) partial[wv] = s;
    __syncthreads();
    if (k == 0) {
      float t = 0.f;
#pragma unroll
      for (int w = 0; w < 8; ++w) t += partial[w];
      float ent = -t;
      total += ent / logK;
    }
    __syncthreads();
  }
  if (k == 0) out[0] = 0.1f * (-(total / 16.0f));
}

// ---------------- launch ----------------
extern "C" void kernel_launch(void* const* d_in, const int* in_sizes, int n_in,
                              void* d_out, int out_size, void* d_ws, size_t ws_size,
                              hipStream_t stream) {
  const float* features  = (const float*)d_in[0];  // (8,2048,1024)
  const float* codebooks = (const float*)d_in[1];  // (16,512,64)
  const float* Wq   = (const float*)d_in[2];       // (1024,1024)
  const float* bq   = (const float*)d_in[3];       // (1024)
  const float* Wout = (const float*)d_in[4];       // (1024,1024)
  const float* bout = (const float*)d_in[5];       // (1024)

  float* out = (float*)d_out;
  float* quantized = out;                 // 16,777,216
  float* targets   = out + 16777216;      // 16,384
  float* losses    = out + 16793600;      // 1

  float* ws     = (float*)d_ws;
  float* q      = ws;                     // 16,777,216 f
  float* q2w    = ws + 16777216;          // 262,144 f
  float* counts = ws + 17039360;          // 8,192 f
  int*   idxw   = (int*)(ws + 17047552);  // 262,144 i  (total 69.2 MB)

  hipLaunchKernelGGL(k_zero, dim3(32), dim3(256), 0, stream, counts, NGRP * NCODE);
  hipLaunchKernelGGL(gemm_nt, dim3(128, 16), dim3(256), 0, stream,
                     features, Wq, bq, q, (const float*)nullptr, (const int*)nullptr, q2w);
  hipLaunchKernelGGL(k2_select, dim3(2048, 16), dim3(256), 0, stream,
                     q, q2w, codebooks, counts, idxw);
  hipLaunchKernelGGL(k_targets, dim3(64), dim3(256), 0, stream, idxw, targets);
  hipLaunchKernelGGL(k_losses, dim3(1), dim3(512), 0, stream, counts, losses);
  hipLaunchKernelGGL(gemm_nt, dim3(128, 16), dim3(256), 0, stream,
                     (const float*)nullptr, Wout, bout, quantized, codebooks, idxw,
                     (float*)nullptr);
}